// Round 5
// baseline (546.270 us; speedup 1.0000x reference)
//
#include <hip/hip_runtime.h>
#include <stdint.h>

#define M_SIMP 100000
#define MPAD   100064
#define NNZV   800000
#define ELLW   16
#define OVF_CAP 8192

typedef unsigned int u32;
typedef __attribute__((ext_vector_type(8))) short short8;
typedef __attribute__((ext_vector_type(4))) float f32x4;

__device__ __forceinline__ float bf2f(u32 u){ return __uint_as_float(u << 16); }
__device__ __forceinline__ u32 f2bf(float f){
    u32 u = __float_as_uint(f);
    return (u + 0x7FFFu + ((u >> 16) & 1u)) >> 16;   // RNE
}

// ---------------- one-pass ELL build (both Laplacians via blockIdx.y) ------
__global__ void k_fill(const int* __restrict__ i0, const float* __restrict__ v0,
                       int* __restrict__ c0, uint2* __restrict__ e0,
                       int* __restrict__ on0, uint4* __restrict__ ov0,
                       const int* __restrict__ i1, const float* __restrict__ v1,
                       int* __restrict__ c1, uint2* __restrict__ e1,
                       int* __restrict__ on1, uint4* __restrict__ ov1){
    int e = blockIdx.x * 256 + threadIdx.x;
    const int* idx   = blockIdx.y ? i1 : i0;
    const float* val = blockIdx.y ? v1 : v0;
    int* cnt   = blockIdx.y ? c1 : c0;
    uint2* ell = blockIdx.y ? e1 : e0;
    int* ovn   = blockIdx.y ? on1 : on0;
    uint4* ovf = blockIdx.y ? ov1 : ov0;
    if (e < NNZV){
        int r = idx[e];
        int c = idx[NNZV + e];
        float v = val[e];
        int k = atomicAdd(&cnt[r], 1);
        if (k < ELLW){
            ell[(size_t)r * ELLW + k] = make_uint2((u32)c, __float_as_uint(v));
        } else {
            int p = atomicAdd(ovn, 1);
            if (p < OVF_CAP) ovf[p] = make_uint4((u32)r, (u32)c, __float_as_uint(v), 0u);
        }
    }
}

// ---------------- transpose x (B,C,M) fp32 -> F0 (M,128) bf16 ----------------
__global__ void k_transpose(const float* __restrict__ x, u32* __restrict__ F0){
    __shared__ unsigned short s[64 * 130];
    int t = threadIdx.x;
    int m0 = blockIdx.x * 64;
    int j  = t & 63;
    int r4 = t >> 6;
    #pragma unroll 4
    for (int it = 0; it < 32; ++it){
        int bc = it * 4 + r4;
        int m  = m0 + j;
        if (m < M_SIMP)
            s[j * 130 + bc] = (unsigned short)f2bf(x[(size_t)bc * M_SIMP + m]);
    }
    __syncthreads();
    #pragma unroll 4
    for (int it = 0; it < 16; ++it){
        int m  = it * 4 + r4;
        int gm = m0 + m;
        if (gm < M_SIMP){
            u32 lo = s[m * 130 + 2 * j];
            u32 hi = s[m * 130 + 2 * j + 1];
            F0[(size_t)gm * 64 + j] = lo | (hi << 16);
        }
    }
}

// ---------------- SpMM from ELL: 16 rows/block, 16 lanes x uint4 per row ----
#define GATHER(c, v)                                                     \
    {                                                                    \
        uint4 g = *(const uint4*)(fin + (size_t)(c) * 64 + l * 4);       \
        a0 += (v)*bf2f(g.x & 0xffffu); a1 += (v)*bf2f(g.x >> 16);        \
        a2 += (v)*bf2f(g.y & 0xffffu); a3 += (v)*bf2f(g.y >> 16);        \
        a4 += (v)*bf2f(g.z & 0xffffu); a5 += (v)*bf2f(g.z >> 16);        \
        a6 += (v)*bf2f(g.w & 0xffffu); a7 += (v)*bf2f(g.w >> 16);        \
    }

__global__ __launch_bounds__(256) void k_spmm(
    const int* __restrict__ cA, const uint2* __restrict__ eA,
    const int* __restrict__ onA, const uint4* __restrict__ ovA,
    const u32* __restrict__ finA, u32* __restrict__ foutA,
    const int* __restrict__ cB, const uint2* __restrict__ eB,
    const int* __restrict__ onB, const uint4* __restrict__ ovB,
    const u32* __restrict__ finB, u32* __restrict__ foutB)
{
    int t   = threadIdx.x;
    int sub = t >> 4;
    int l   = t & 15;
    int row = blockIdx.x * 16 + sub;
    const int* cntp; const uint2* ell; const int* ovn; const uint4* ovf;
    const u32* fin; u32* fout;
    if (blockIdx.y == 0){ cntp=cA; ell=eA; ovn=onA; ovf=ovA; fin=finA; fout=foutA; }
    else                { cntp=cB; ell=eB; ovn=onB; ovf=ovB; fin=finB; fout=foutB; }
    if (row >= M_SIMP) return;

    int cnt = cntp[row];
    const uint2* er = ell + (size_t)row * ELLW;
    uint2 pr = er[l];                         // pairs 0..15, register-resident
    int creg = (int)pr.x;
    int vreg = (int)pr.y;

    float a0=0,a1=0,a2=0,a3=0,a4=0,a5=0,a6=0,a7=0;
    int n1 = cnt < ELLW ? cnt : ELLW;
    int j = 0;
    for (; j + 4 <= n1; j += 4){
        int   c0 = __shfl(creg, j,   16), c1 = __shfl(creg, j+1, 16);
        int   c2 = __shfl(creg, j+2, 16), c3 = __shfl(creg, j+3, 16);
        float v0 = __uint_as_float((u32)__shfl(vreg, j,   16));
        float v1 = __uint_as_float((u32)__shfl(vreg, j+1, 16));
        float v2 = __uint_as_float((u32)__shfl(vreg, j+2, 16));
        float v3 = __uint_as_float((u32)__shfl(vreg, j+3, 16));
        uint4 g0 = *(const uint4*)(fin + (size_t)c0 * 64 + l * 4);
        uint4 g1 = *(const uint4*)(fin + (size_t)c1 * 64 + l * 4);
        uint4 g2 = *(const uint4*)(fin + (size_t)c2 * 64 + l * 4);
        uint4 g3 = *(const uint4*)(fin + (size_t)c3 * 64 + l * 4);
        a0 += v0*bf2f(g0.x&0xffffu) + v1*bf2f(g1.x&0xffffu) + v2*bf2f(g2.x&0xffffu) + v3*bf2f(g3.x&0xffffu);
        a1 += v0*bf2f(g0.x>>16)     + v1*bf2f(g1.x>>16)     + v2*bf2f(g2.x>>16)     + v3*bf2f(g3.x>>16);
        a2 += v0*bf2f(g0.y&0xffffu) + v1*bf2f(g1.y&0xffffu) + v2*bf2f(g2.y&0xffffu) + v3*bf2f(g3.y&0xffffu);
        a3 += v0*bf2f(g0.y>>16)     + v1*bf2f(g1.y>>16)     + v2*bf2f(g2.y>>16)     + v3*bf2f(g3.y>>16);
        a4 += v0*bf2f(g0.z&0xffffu) + v1*bf2f(g1.z&0xffffu) + v2*bf2f(g2.z&0xffffu) + v3*bf2f(g3.z&0xffffu);
        a5 += v0*bf2f(g0.z>>16)     + v1*bf2f(g1.z>>16)     + v2*bf2f(g2.z>>16)     + v3*bf2f(g3.z>>16);
        a6 += v0*bf2f(g0.w&0xffffu) + v1*bf2f(g1.w&0xffffu) + v2*bf2f(g2.w&0xffffu) + v3*bf2f(g3.w&0xffffu);
        a7 += v0*bf2f(g0.w>>16)     + v1*bf2f(g1.w>>16)     + v2*bf2f(g2.w>>16)     + v3*bf2f(g3.w>>16);
    }
    for (; j < n1; j++){
        int   c = __shfl(creg, j, 16);
        float v = __uint_as_float((u32)__shfl(vreg, j, 16));
        GATHER(c, v)
    }
    if (cnt > ELLW){
        int n = *ovn; if (n > OVF_CAP) n = OVF_CAP;
        for (int i = 0; i < n; i++){
            uint4 o = ovf[i];
            if ((int)o.x == row){
                float v = __uint_as_float(o.z);
                GATHER((int)o.y, v)
            }
        }
    }
    uint4 o;
    o.x = f2bf(a0) | (f2bf(a1) << 16);
    o.y = f2bf(a2) | (f2bf(a3) << 16);
    o.z = f2bf(a4) | (f2bf(a5) << 16);
    o.w = f2bf(a6) | (f2bf(a7) << 16);
    *(uint4*)(fout + (size_t)row * 64 + l * 4) = o;
}

// ---------------- theta (o,i,k) fp32 -> Wb bf16, 5 slices [s][o][i] ---------
// s=0: th0+th3 (F0)   s=1: th1 (F1)   s=2: th4 (F4)   s=3: th2 (F2)   s=4: th5 (F5)
__global__ void k_wb(const float* __restrict__ theta, u32* __restrict__ Wb){
    int idx = blockIdx.x * 256 + threadIdx.x;     // over 5*64*32 u32
    if (idx < 5 * 64 * 32){
        int s  = idx >> 11;
        int r  = idx & 2047;
        int o  = r >> 5;
        int i2 = (r & 31) * 2;
        const int ks[5] = {0, 1, 4, 2, 5};
        float wlo, whi;
        if (s == 0){
            wlo = theta[o*384 + i2*6 + 0]     + theta[o*384 + i2*6 + 3];
            whi = theta[o*384 + (i2+1)*6 + 0] + theta[o*384 + (i2+1)*6 + 3];
        } else {
            wlo = theta[o*384 + i2*6 + ks[s]];
            whi = theta[o*384 + (i2+1)*6 + ks[s]];
        }
        Wb[idx] = f2bf(wlo) | (f2bf(whi) << 16);
    }
}

// ---------------- MFMA GEMM, templated pass (NK slices, accumulate flag) ----
template<int NK, bool ACC>
__global__ __launch_bounds__(256) void k_gemm(
    const u32* __restrict__ Fa, const u32* __restrict__ Fb, const u32* __restrict__ Fc,
    const u32* __restrict__ Wb, const float* __restrict__ bias, float* __restrict__ out)
{
    int t    = threadIdx.x;
    int wave = t >> 6;
    int lane = t & 63;
    int q    = lane >> 4;
    int l16  = lane & 15;
    int bm   = blockIdx.x * 64;
    int b    = blockIdx.y;
    const u32* __restrict__ Fs[3] = {Fa, Fb, Fc};

    f32x4 acc0 = {0.f,0.f,0.f,0.f}, acc1 = {0.f,0.f,0.f,0.f};
    f32x4 acc2 = {0.f,0.f,0.f,0.f}, acc3 = {0.f,0.f,0.f,0.f};

    int o_a = wave * 16 + l16;
    size_t mr0 = (size_t)(bm +  0 + l16) * 64 + b * 32;
    size_t mr1 = (size_t)(bm + 16 + l16) * 64 + b * 32;
    size_t mr2 = (size_t)(bm + 32 + l16) * 64 + b * 32;
    size_t mr3 = (size_t)(bm + 48 + l16) * 64 + b * 32;

    #pragma unroll
    for (int km = 0; km < NK; km++){
        const u32* __restrict__ F = Fs[km];
        const u32* __restrict__ W = Wb + (km * 64 + o_a) * 32;
        #pragma unroll
        for (int h = 0; h < 2; h++){
            int koff = h * 16 + q * 4;
            short8 a   = *(const short8*)(W + koff);
            short8 bb0 = *(const short8*)(F + mr0 + koff);
            short8 bb1 = *(const short8*)(F + mr1 + koff);
            short8 bb2 = *(const short8*)(F + mr2 + koff);
            short8 bb3 = *(const short8*)(F + mr3 + koff);
            acc0 = __builtin_amdgcn_mfma_f32_16x16x32_bf16(a, bb0, acc0, 0, 0, 0);
            acc1 = __builtin_amdgcn_mfma_f32_16x16x32_bf16(a, bb1, acc1, 0, 0, 0);
            acc2 = __builtin_amdgcn_mfma_f32_16x16x32_bf16(a, bb2, acc2, 0, 0, 0);
            acc3 = __builtin_amdgcn_mfma_f32_16x16x32_bf16(a, bb3, acc3, 0, 0, 0);
        }
    }

    int ob = wave * 16 + q * 4;
    float bv0 = bias[ob], bv1 = bias[ob+1], bv2 = bias[ob+2], bv3 = bias[ob+3];
    f32x4 accs[4] = {acc0, acc1, acc2, acc3};
    #pragma unroll
    for (int ms = 0; ms < 4; ms++){
        int gm = bm + ms * 16 + l16;
        if (gm < M_SIMP){
            size_t base = (size_t)(b * 64 + ob) * M_SIMP + gm;
            if (ACC){
                out[base             ] += accs[ms][0];
                out[base + 1ul*M_SIMP] += accs[ms][1];
                out[base + 2ul*M_SIMP] += accs[ms][2];
                out[base + 3ul*M_SIMP] += accs[ms][3];
            } else {
                out[base             ] = accs[ms][0] + bv0;
                out[base + 1ul*M_SIMP] = accs[ms][1] + bv1;
                out[base + 2ul*M_SIMP] = accs[ms][2] + bv2;
                out[base + 3ul*M_SIMP] = accs[ms][3] + bv3;
            }
        }
    }
}

extern "C" void kernel_launch(void* const* d_in, const int* in_sizes, int n_in,
                              void* d_out, int out_size, void* d_ws, size_t ws_size,
                              hipStream_t stream)
{
    const int*   Ll_idx = (const int*)d_in[0];
    const float* Ll_val = (const float*)d_in[1];
    const int*   Lu_idx = (const int*)d_in[2];
    const float* Lu_val = (const float*)d_in[3];
    const float* x      = (const float*)d_in[4];
    const float* theta  = (const float*)d_in[5];
    const float* bias   = (const float*)d_in[6];
    float* out = (float*)d_out;

    char* ws = (char*)d_ws;
    size_t off = 0;
    auto take = [&](size_t bytes) -> char* {
        char* p = ws + off;
        off = (off + bytes + 255) & ~(size_t)255;
        return p;
    };
    const size_t FB = (size_t)MPAD * 64 * 4;     // 25.6 MB per bf16 feature map
    u32* B0 = (u32*)take(FB);                    // F0, later F5
    u32* B1 = (u32*)take(FB);                    // F1
    u32* B2 = (u32*)take(FB);                    // F4
    u32* B3 = (u32*)take(FB);                    // F2
    u32* Wb = (u32*)take((size_t)5 * 64 * 32 * 4);
    int* cnt_l = (int*)take((size_t)(M_SIMP + 64) * 4);
    int* ovn_l = cnt_l + M_SIMP;
    int* cnt_u = (int*)take((size_t)(M_SIMP + 64) * 4);
    int* ovn_u = cnt_u + M_SIMP;
    uint2* ell_l = (uint2*)take(((size_t)M_SIMP * ELLW + 64) * 8);
    uint2* ell_u = (uint2*)take(((size_t)M_SIMP * ELLW + 64) * 8);
    uint4* ovf_l = (uint4*)take((size_t)OVF_CAP * 16);
    uint4* ovf_u = (uint4*)take((size_t)OVF_CAP * 16);
    // total ~129.2 MB — below the 142.5 MB footprint proven safe in rounds 1-3

    hipMemsetAsync(cnt_l, 0, (size_t)(M_SIMP + 1) * 4, stream);
    hipMemsetAsync(cnt_u, 0, (size_t)(M_SIMP + 1) * 4, stream);

    const int NBH = (NNZV + 255) / 256;       // 3125
    dim3 gh(NBH, 2);
    k_fill<<<gh, 256, 0, stream>>>(Ll_idx, Ll_val, cnt_l, ell_l, ovn_l, ovf_l,
                                   Lu_idx, Lu_val, cnt_u, ell_u, ovn_u, ovf_u);

    const int NBT = (M_SIMP + 63) / 64;       // 1563
    k_transpose<<<NBT, 256, 0, stream>>>(x, B0);
    k_wb<<<(5 * 64 * 32 + 255) / 256, 256, 0, stream>>>(theta, Wb);

    const int NBM = (M_SIMP + 15) / 16;       // 6250
    dim3 gm(NBM, 2);
    // step 1: F1 = Ll*F0 -> B1  ||  F4 = Lu*F0 -> B2
    k_spmm<<<gm, 256, 0, stream>>>(cnt_l, ell_l, ovn_l, ovf_l, B0, B1,
                                   cnt_u, ell_u, ovn_u, ovf_u, B0, B2);

    dim3 gg(NBT, 2);
    // pass A: out = bias + (th0+th3)*F0 + th1*F1 + th4*F4
    k_gemm<3, false><<<gg, 256, 0, stream>>>(B0, B1, B2, Wb, bias, out);

    // step 2: F2 = Ll*F1 -> B3  ||  F5 = Lu*F4 -> B0 (B0 dead after pass A)
    k_spmm<<<gm, 256, 0, stream>>>(cnt_l, ell_l, ovn_l, ovf_l, B1, B3,
                                   cnt_u, ell_u, ovn_u, ovf_u, B2, B0);

    // pass B: out += th2*F2 + th5*F5
    k_gemm<2, true><<<gg, 256, 0, stream>>>(B3, B0, B0, Wb + 3 * 64 * 32, bias, out);
}

// Round 6
// 542.036 us; speedup vs baseline: 1.0078x; 1.0078x over previous
//
#include <hip/hip_runtime.h>
#include <stdint.h>

#define M_SIMP 100000
#define MPAD   100064
#define NNZV   800000
#define ELLW   16
#define OVF_CAP 8192

typedef unsigned int u32;
typedef __attribute__((ext_vector_type(8))) short short8;
typedef __attribute__((ext_vector_type(4))) float f32x4;
typedef __attribute__((ext_vector_type(4))) u32 u32x4;

__device__ __forceinline__ float bf2f(u32 u){ return __uint_as_float(u << 16); }
__device__ __forceinline__ u32 f2bf(float f){
    u32 u = __float_as_uint(f);
    return (u + 0x7FFFu + ((u >> 16) & 1u)) >> 16;   // RNE
}

// ============ fused prep: ELL fill (both L) + transpose + W repack =========
// roles by blockIdx.x: [0,NBF) fill, [NBF,NBF+NBT) transpose, then 40 wb blocks
#define NBF 1563
#define NBT 1563
#define NBW 40

__global__ __launch_bounds__(256) void k_prep(
    const int* __restrict__ Ll_idx, const float* __restrict__ Ll_val,
    const int* __restrict__ Lu_idx, const float* __restrict__ Lu_val,
    int* __restrict__ cnt_l, unsigned long long* __restrict__ ell_l,
    int* __restrict__ ovn_l, uint4* __restrict__ ovf_l,
    int* __restrict__ cnt_u, unsigned long long* __restrict__ ell_u,
    int* __restrict__ ovn_u, uint4* __restrict__ ovf_u,
    const float* __restrict__ x, u32* __restrict__ F0,
    const float* __restrict__ theta, u32* __restrict__ Wb)
{
    __shared__ unsigned short s[64 * 130];
    int t  = threadIdx.x;
    int bx = blockIdx.x;

    if (bx < NBF){
        // ---- ELL fill: 4 edges per thread, both matrices in one edge space
        int tid = bx * 256 + t;
        if (tid < 400000){
            int e4  = tid * 4;                    // 0 .. 1.6M, never straddles 800k
            int mat = e4 >= NNZV;
            int le  = mat ? e4 - NNZV : e4;
            const int*   idx = mat ? Lu_idx : Ll_idx;
            const float* val = mat ? Lu_val : Ll_val;
            int* cnt  = mat ? cnt_u : cnt_l;
            unsigned long long* ell = mat ? ell_u : ell_l;
            int* ovn  = mat ? ovn_u : ovn_l;
            uint4* ovf = mat ? ovf_u : ovf_l;
            int4   r4 = *(const int4*)(idx + le);
            int4   c4 = *(const int4*)(idx + NNZV + le);
            float4 v4 = *(const float4*)(val + le);
            int   rs[4] = {r4.x, r4.y, r4.z, r4.w};
            int   cs[4] = {c4.x, c4.y, c4.z, c4.w};
            float vs[4] = {v4.x, v4.y, v4.z, v4.w};
            #pragma unroll
            for (int j = 0; j < 4; j++){
                int k = atomicAdd(&cnt[rs[j]], 1);
                unsigned long long pk = (u32)cs[j] |
                    ((unsigned long long)__float_as_uint(vs[j]) << 32);
                if (k < ELLW){
                    __builtin_nontemporal_store(pk, &ell[(size_t)rs[j] * ELLW + k]);
                } else {
                    int p = atomicAdd(ovn, 1);
                    if (p < OVF_CAP)
                        ovf[p] = make_uint4((u32)rs[j], (u32)cs[j], __float_as_uint(vs[j]), 0u);
                }
            }
        }
    } else if (bx < NBF + NBT){
        // ---- transpose x (B,C,M) fp32 -> F0 (M,128) bf16
        int m0 = (bx - NBF) * 64;
        int j  = t & 63;
        int r4 = t >> 6;
        #pragma unroll 4
        for (int it = 0; it < 32; ++it){
            int bc = it * 4 + r4;
            int m  = m0 + j;
            if (m < M_SIMP)
                s[j * 130 + bc] = (unsigned short)f2bf(x[(size_t)bc * M_SIMP + m]);
        }
        __syncthreads();
        #pragma unroll 4
        for (int it = 0; it < 16; ++it){
            int m  = it * 4 + r4;
            int gm = m0 + m;
            if (gm < M_SIMP){
                u32 lo = s[m * 130 + 2 * j];
                u32 hi = s[m * 130 + 2 * j + 1];
                __builtin_nontemporal_store(lo | (hi << 16), &F0[(size_t)gm * 64 + j]);
            }
        }
    } else {
        // ---- theta (o,i,k) fp32 -> Wb bf16, 5 slices [s][o][i]
        // s=0: th0+th3   s=1: th1   s=2: th4   s=3: th2   s=4: th5
        int idx = (bx - NBF - NBT) * 256 + t;
        if (idx < 5 * 64 * 32){
            int sl = idx >> 11;
            int r  = idx & 2047;
            int o  = r >> 5;
            int i2 = (r & 31) * 2;
            const int ks[5] = {0, 1, 4, 2, 5};
            float wlo, whi;
            if (sl == 0){
                wlo = theta[o*384 + i2*6 + 0]     + theta[o*384 + i2*6 + 3];
                whi = theta[o*384 + (i2+1)*6 + 0] + theta[o*384 + (i2+1)*6 + 3];
            } else {
                wlo = theta[o*384 + i2*6 + ks[sl]];
                whi = theta[o*384 + (i2+1)*6 + ks[sl]];
            }
            Wb[idx] = f2bf(wlo) | (f2bf(whi) << 16);
        }
    }
}

// ---------------- SpMM from ELL: 16 rows/block-quarter, unroll-8 -----------
#define GATHER(c, v)                                                     \
    {                                                                    \
        uint4 g = *(const uint4*)(fin + (size_t)(c) * 64 + l * 4);       \
        a0 += (v)*bf2f(g.x & 0xffffu); a1 += (v)*bf2f(g.x >> 16);        \
        a2 += (v)*bf2f(g.y & 0xffffu); a3 += (v)*bf2f(g.y >> 16);        \
        a4 += (v)*bf2f(g.z & 0xffffu); a5 += (v)*bf2f(g.z >> 16);        \
        a6 += (v)*bf2f(g.w & 0xffffu); a7 += (v)*bf2f(g.w >> 16);        \
    }

__global__ __launch_bounds__(256) void k_spmm(
    const int* __restrict__ cA, const uint2* __restrict__ eA,
    const int* __restrict__ onA, const uint4* __restrict__ ovA,
    const u32* __restrict__ finA, u32* __restrict__ foutA,
    const int* __restrict__ cB, const uint2* __restrict__ eB,
    const int* __restrict__ onB, const uint4* __restrict__ ovB,
    const u32* __restrict__ finB, u32* __restrict__ foutB)
{
    int t    = threadIdx.x;
    int lane = t & 63;
    int l    = t & 15;
    int row  = blockIdx.x * 16 + (t >> 4);
    const int* cntp; const uint2* ell; const int* ovn; const uint4* ovf;
    const u32* fin; u32* fout;
    if (blockIdx.y == 0){ cntp=cA; ell=eA; ovn=onA; ovf=ovA; fin=finA; fout=foutA; }
    else                { cntp=cB; ell=eB; ovn=onB; ovf=ovB; fin=finB; fout=foutB; }
    if (row >= M_SIMP) return;

    int cnt = cntp[row];
    uint2 pr = ell[(size_t)row * ELLW + l];   // pairs 0..15, register-resident
    int creg = (int)pr.x;
    int vreg = (int)pr.y;

    float a0=0,a1=0,a2=0,a3=0,a4=0,a5=0,a6=0,a7=0;
    int n1 = cnt < ELLW ? cnt : ELLW;
    int j = 0;
    for (; j + 8 <= n1; j += 8){
        int   c0 = __shfl(creg, j,   16), c1 = __shfl(creg, j+1, 16);
        int   c2 = __shfl(creg, j+2, 16), c3 = __shfl(creg, j+3, 16);
        int   c4 = __shfl(creg, j+4, 16), c5 = __shfl(creg, j+5, 16);
        int   c6 = __shfl(creg, j+6, 16), c7 = __shfl(creg, j+7, 16);
        float v0 = __uint_as_float((u32)__shfl(vreg, j,   16));
        float v1 = __uint_as_float((u32)__shfl(vreg, j+1, 16));
        float v2 = __uint_as_float((u32)__shfl(vreg, j+2, 16));
        float v3 = __uint_as_float((u32)__shfl(vreg, j+3, 16));
        float v4 = __uint_as_float((u32)__shfl(vreg, j+4, 16));
        float v5 = __uint_as_float((u32)__shfl(vreg, j+5, 16));
        float v6 = __uint_as_float((u32)__shfl(vreg, j+6, 16));
        float v7 = __uint_as_float((u32)__shfl(vreg, j+7, 16));
        uint4 g0 = *(const uint4*)(fin + (size_t)c0 * 64 + l * 4);
        uint4 g1 = *(const uint4*)(fin + (size_t)c1 * 64 + l * 4);
        uint4 g2 = *(const uint4*)(fin + (size_t)c2 * 64 + l * 4);
        uint4 g3 = *(const uint4*)(fin + (size_t)c3 * 64 + l * 4);
        uint4 g4 = *(const uint4*)(fin + (size_t)c4 * 64 + l * 4);
        uint4 g5 = *(const uint4*)(fin + (size_t)c5 * 64 + l * 4);
        uint4 g6 = *(const uint4*)(fin + (size_t)c6 * 64 + l * 4);
        uint4 g7 = *(const uint4*)(fin + (size_t)c7 * 64 + l * 4);
        a0 += v0*bf2f(g0.x&0xffffu) + v1*bf2f(g1.x&0xffffu) + v2*bf2f(g2.x&0xffffu) + v3*bf2f(g3.x&0xffffu)
            + v4*bf2f(g4.x&0xffffu) + v5*bf2f(g5.x&0xffffu) + v6*bf2f(g6.x&0xffffu) + v7*bf2f(g7.x&0xffffu);
        a1 += v0*bf2f(g0.x>>16)     + v1*bf2f(g1.x>>16)     + v2*bf2f(g2.x>>16)     + v3*bf2f(g3.x>>16)
            + v4*bf2f(g4.x>>16)     + v5*bf2f(g5.x>>16)     + v6*bf2f(g6.x>>16)     + v7*bf2f(g7.x>>16);
        a2 += v0*bf2f(g0.y&0xffffu) + v1*bf2f(g1.y&0xffffu) + v2*bf2f(g2.y&0xffffu) + v3*bf2f(g3.y&0xffffu)
            + v4*bf2f(g4.y&0xffffu) + v5*bf2f(g5.y&0xffffu) + v6*bf2f(g6.y&0xffffu) + v7*bf2f(g7.y&0xffffu);
        a3 += v0*bf2f(g0.y>>16)     + v1*bf2f(g1.y>>16)     + v2*bf2f(g2.y>>16)     + v3*bf2f(g3.y>>16)
            + v4*bf2f(g4.y>>16)     + v5*bf2f(g5.y>>16)     + v6*bf2f(g6.y>>16)     + v7*bf2f(g7.y>>16);
        a4 += v0*bf2f(g0.z&0xffffu) + v1*bf2f(g1.z&0xffffu) + v2*bf2f(g2.z&0xffffu) + v3*bf2f(g3.z&0xffffu)
            + v4*bf2f(g4.z&0xffffu) + v5*bf2f(g5.z&0xffffu) + v6*bf2f(g6.z&0xffffu) + v7*bf2f(g7.z&0xffffu);
        a5 += v0*bf2f(g0.z>>16)     + v1*bf2f(g1.z>>16)     + v2*bf2f(g2.z>>16)     + v3*bf2f(g3.z>>16)
            + v4*bf2f(g4.z>>16)     + v5*bf2f(g5.z>>16)     + v6*bf2f(g6.z>>16)     + v7*bf2f(g7.z>>16);
        a6 += v0*bf2f(g0.w&0xffffu) + v1*bf2f(g1.w&0xffffu) + v2*bf2f(g2.w&0xffffu) + v3*bf2f(g3.w&0xffffu)
            + v4*bf2f(g4.w&0xffffu) + v5*bf2f(g5.w&0xffffu) + v6*bf2f(g6.w&0xffffu) + v7*bf2f(g7.w&0xffffu);
        a7 += v0*bf2f(g0.w>>16)     + v1*bf2f(g1.w>>16)     + v2*bf2f(g2.w>>16)     + v3*bf2f(g3.w>>16)
            + v4*bf2f(g4.w>>16)     + v5*bf2f(g5.w>>16)     + v6*bf2f(g6.w>>16)     + v7*bf2f(g7.w>>16);
    }
    for (; j + 4 <= n1; j += 4){
        int   c0 = __shfl(creg, j,   16), c1 = __shfl(creg, j+1, 16);
        int   c2 = __shfl(creg, j+2, 16), c3 = __shfl(creg, j+3, 16);
        float v0 = __uint_as_float((u32)__shfl(vreg, j,   16));
        float v1 = __uint_as_float((u32)__shfl(vreg, j+1, 16));
        float v2 = __uint_as_float((u32)__shfl(vreg, j+2, 16));
        float v3 = __uint_as_float((u32)__shfl(vreg, j+3, 16));
        uint4 g0 = *(const uint4*)(fin + (size_t)c0 * 64 + l * 4);
        uint4 g1 = *(const uint4*)(fin + (size_t)c1 * 64 + l * 4);
        uint4 g2 = *(const uint4*)(fin + (size_t)c2 * 64 + l * 4);
        uint4 g3 = *(const uint4*)(fin + (size_t)c3 * 64 + l * 4);
        a0 += v0*bf2f(g0.x&0xffffu) + v1*bf2f(g1.x&0xffffu) + v2*bf2f(g2.x&0xffffu) + v3*bf2f(g3.x&0xffffu);
        a1 += v0*bf2f(g0.x>>16)     + v1*bf2f(g1.x>>16)     + v2*bf2f(g2.x>>16)     + v3*bf2f(g3.x>>16);
        a2 += v0*bf2f(g0.y&0xffffu) + v1*bf2f(g1.y&0xffffu) + v2*bf2f(g2.y&0xffffu) + v3*bf2f(g3.y&0xffffu);
        a3 += v0*bf2f(g0.y>>16)     + v1*bf2f(g1.y>>16)     + v2*bf2f(g2.y>>16)     + v3*bf2f(g3.y>>16);
        a4 += v0*bf2f(g0.z&0xffffu) + v1*bf2f(g1.z&0xffffu) + v2*bf2f(g2.z&0xffffu) + v3*bf2f(g3.z&0xffffu);
        a5 += v0*bf2f(g0.z>>16)     + v1*bf2f(g1.z>>16)     + v2*bf2f(g2.z>>16)     + v3*bf2f(g3.z>>16);
        a6 += v0*bf2f(g0.w&0xffffu) + v1*bf2f(g1.w&0xffffu) + v2*bf2f(g2.w&0xffffu) + v3*bf2f(g3.w&0xffffu);
        a7 += v0*bf2f(g0.w>>16)     + v1*bf2f(g1.w>>16)     + v2*bf2f(g2.w>>16)     + v3*bf2f(g3.w>>16);
    }
    for (; j < n1; j++){
        int   c = __shfl(creg, j, 16);
        float v = __uint_as_float((u32)__shfl(vreg, j, 16));
        GATHER(c, v)
    }
    if (cnt > ELLW){
        // parallel overflow scan: 16 lanes stride the list, ballot + shfl
        int n = *ovn; if (n > OVF_CAP) n = OVF_CAP;
        for (int i0 = 0; i0 < n; i0 += 16){
            int i = i0 + l;
            u32 orow = 0xffffffffu; int oc = 0, ov = 0;
            if (i < n){
                uint4 o = ovf[i];
                orow = o.x; oc = (int)o.y; ov = (int)o.z;
            }
            unsigned long long bal = __ballot(orow == (u32)row);
            u32 mask = (u32)((bal >> (lane & 48)) & 0xFFFFull);
            while (mask){
                int jj = __ffs(mask) - 1; mask &= mask - 1;
                int   c = __shfl(oc, jj, 16);
                float v = __uint_as_float((u32)__shfl(ov, jj, 16));
                GATHER(c, v)
            }
        }
    }
    u32x4 o;
    o.x = f2bf(a0) | (f2bf(a1) << 16);
    o.y = f2bf(a2) | (f2bf(a3) << 16);
    o.z = f2bf(a4) | (f2bf(a5) << 16);
    o.w = f2bf(a6) | (f2bf(a7) << 16);
    __builtin_nontemporal_store(o, (u32x4*)(fout + (size_t)row * 64 + l * 4));
}

// ---------------- MFMA GEMM, templated pass (NK slices, accumulate flag) ----
template<int NK, bool ACC>
__global__ __launch_bounds__(256) void k_gemm(
    const u32* __restrict__ Fa, const u32* __restrict__ Fb, const u32* __restrict__ Fc,
    const u32* __restrict__ Wb, const float* __restrict__ bias, float* __restrict__ out)
{
    int t    = threadIdx.x;
    int wave = t >> 6;
    int lane = t & 63;
    int q    = lane >> 4;
    int l16  = lane & 15;
    int bm   = blockIdx.x * 64;
    int b    = blockIdx.y;
    const u32* __restrict__ Fs[3] = {Fa, Fb, Fc};

    f32x4 acc0 = {0.f,0.f,0.f,0.f}, acc1 = {0.f,0.f,0.f,0.f};
    f32x4 acc2 = {0.f,0.f,0.f,0.f}, acc3 = {0.f,0.f,0.f,0.f};

    int o_a = wave * 16 + l16;
    size_t mr0 = (size_t)(bm +  0 + l16) * 64 + b * 32;
    size_t mr1 = (size_t)(bm + 16 + l16) * 64 + b * 32;
    size_t mr2 = (size_t)(bm + 32 + l16) * 64 + b * 32;
    size_t mr3 = (size_t)(bm + 48 + l16) * 64 + b * 32;

    #pragma unroll
    for (int km = 0; km < NK; km++){
        const u32* __restrict__ F = Fs[km];
        const u32* __restrict__ W = Wb + (km * 64 + o_a) * 32;
        #pragma unroll
        for (int h = 0; h < 2; h++){
            int koff = h * 16 + q * 4;
            short8 a   = *(const short8*)(W + koff);
            short8 bb0 = *(const short8*)(F + mr0 + koff);
            short8 bb1 = *(const short8*)(F + mr1 + koff);
            short8 bb2 = *(const short8*)(F + mr2 + koff);
            short8 bb3 = *(const short8*)(F + mr3 + koff);
            acc0 = __builtin_amdgcn_mfma_f32_16x16x32_bf16(a, bb0, acc0, 0, 0, 0);
            acc1 = __builtin_amdgcn_mfma_f32_16x16x32_bf16(a, bb1, acc1, 0, 0, 0);
            acc2 = __builtin_amdgcn_mfma_f32_16x16x32_bf16(a, bb2, acc2, 0, 0, 0);
            acc3 = __builtin_amdgcn_mfma_f32_16x16x32_bf16(a, bb3, acc3, 0, 0, 0);
        }
    }

    int ob = wave * 16 + q * 4;
    float bv0 = bias[ob], bv1 = bias[ob+1], bv2 = bias[ob+2], bv3 = bias[ob+3];
    f32x4 accs[4] = {acc0, acc1, acc2, acc3};
    #pragma unroll
    for (int ms = 0; ms < 4; ms++){
        int gm = bm + ms * 16 + l16;
        if (gm < M_SIMP){
            size_t base = (size_t)(b * 64 + ob) * M_SIMP + gm;
            if (ACC){
                out[base             ] += accs[ms][0];
                out[base + 1ul*M_SIMP] += accs[ms][1];
                out[base + 2ul*M_SIMP] += accs[ms][2];
                out[base + 3ul*M_SIMP] += accs[ms][3];
            } else {
                __builtin_nontemporal_store(accs[ms][0] + bv0, &out[base             ]);
                __builtin_nontemporal_store(accs[ms][1] + bv1, &out[base + 1ul*M_SIMP]);
                __builtin_nontemporal_store(accs[ms][2] + bv2, &out[base + 2ul*M_SIMP]);
                __builtin_nontemporal_store(accs[ms][3] + bv3, &out[base + 3ul*M_SIMP]);
            }
        }
    }
}

extern "C" void kernel_launch(void* const* d_in, const int* in_sizes, int n_in,
                              void* d_out, int out_size, void* d_ws, size_t ws_size,
                              hipStream_t stream)
{
    const int*   Ll_idx = (const int*)d_in[0];
    const float* Ll_val = (const float*)d_in[1];
    const int*   Lu_idx = (const int*)d_in[2];
    const float* Lu_val = (const float*)d_in[3];
    const float* x      = (const float*)d_in[4];
    const float* theta  = (const float*)d_in[5];
    const float* bias   = (const float*)d_in[6];
    float* out = (float*)d_out;

    char* ws = (char*)d_ws;
    size_t off = 0;
    auto take = [&](size_t bytes) -> char* {
        char* p = ws + off;
        off = (off + bytes + 255) & ~(size_t)255;
        return p;
    };
    const size_t FB = (size_t)MPAD * 64 * 4;     // 25.6 MB per bf16 feature map
    u32* B0 = (u32*)take(FB);                    // F0, later F5
    u32* B1 = (u32*)take(FB);                    // F1
    u32* B2 = (u32*)take(FB);                    // F4
    u32* B3 = (u32*)take(FB);                    // F2
    u32* Wb = (u32*)take((size_t)5 * 64 * 32 * 4);
    int* cnt_l = (int*)take((size_t)(M_SIMP + 64) * 4);
    int* ovn_l = cnt_l + M_SIMP;
    int* cnt_u = (int*)take((size_t)(M_SIMP + 64) * 4);
    int* ovn_u = cnt_u + M_SIMP;
    unsigned long long* ell_l = (unsigned long long*)take(((size_t)M_SIMP * ELLW + 64) * 8);
    unsigned long long* ell_u = (unsigned long long*)take(((size_t)M_SIMP * ELLW + 64) * 8);
    uint4* ovf_l = (uint4*)take((size_t)OVF_CAP * 16);
    uint4* ovf_u = (uint4*)take((size_t)OVF_CAP * 16);
    // total ~129.2 MB — below the 142.5 MB footprint proven safe in rounds 1-3

    hipMemsetAsync(cnt_l, 0, (size_t)(M_SIMP + 1) * 4, stream);
    hipMemsetAsync(cnt_u, 0, (size_t)(M_SIMP + 1) * 4, stream);

    // fused prep: fill + transpose + wb
    k_prep<<<NBF + NBT + NBW, 256, 0, stream>>>(
        Ll_idx, Ll_val, Lu_idx, Lu_val,
        cnt_l, ell_l, ovn_l, ovf_l,
        cnt_u, ell_u, ovn_u, ovf_u,
        x, B0, theta, Wb);

    const int NBM = (M_SIMP + 15) / 16;       // 6250
    dim3 gm(NBM, 2);
    // step 1: F1 = Ll*F0 -> B1  ||  F4 = Lu*F0 -> B2
    k_spmm<<<gm, 256, 0, stream>>>(cnt_l, (const uint2*)ell_l, ovn_l, ovf_l, B0, B1,
                                   cnt_u, (const uint2*)ell_u, ovn_u, ovf_u, B0, B2);

    dim3 gg(NBT, 2);
    // pass A: out = bias + (th0+th3)*F0 + th1*F1 + th4*F4
    k_gemm<3, false><<<gg, 256, 0, stream>>>(B0, B1, B2, Wb, bias, out);

    // step 2: F2 = Ll*F1 -> B3  ||  F5 = Lu*F4 -> B0 (B0 dead after pass A)
    k_spmm<<<gm, 256, 0, stream>>>(cnt_l, (const uint2*)ell_l, ovn_l, ovf_l, B1, B3,
                                   cnt_u, (const uint2*)ell_u, ovn_u, ovf_u, B2, B0);

    // pass B: out += th2*F2 + th5*F5
    k_gemm<2, true><<<gg, 256, 0, stream>>>(B3, B0, B0, Wb + 3 * 64 * 32, bias, out);
}